// Round 3
// baseline (741.765 us; speedup 1.0000x reference)
//
#include <hip/hip_runtime.h>

// Problem constants
#define D     1024
#define H     8
#define M     2048
#define IMG   49152          // 128*128*3
#define IMG4  12288          // IMG/4

typedef float nfloat4 __attribute__((ext_vector_type(4)));  // native vec for nontemporal builtins

// Workspace layout (in floats)
#define WS_Q      0          // [H*D]       = 8192
#define WS_P      8192       // [H*D]       = 8192  (atomic-accumulated, must be zeroed)
#define WS_BK     16384      // [H]         (padded to 64)
#define WS_LOGITS 16448      // [H*M]       = 16384
#define WS_W      32832      // [H*M]       = 16384
// total 49216 floats = 196,864 bytes

// ---------------------------------------------------------------------------
// Kernel A: q[h,e] = sum_d Q[d]*WQ[h,e,d] + bQ[h,e]
// One wave per (h,e). 8192 waves -> 2048 blocks of 256.
__global__ __launch_bounds__(256) void qproj_kernel(
    const float* __restrict__ Q, const float* __restrict__ WQ,
    const float* __restrict__ bQ, float* __restrict__ q_out) {
  int wave = (blockIdx.x * 256 + threadIdx.x) >> 6;
  int lane = threadIdx.x & 63;
  int h = wave >> 10;
  int e = wave & 1023;
  const float4* Wrow = (const float4*)(WQ + (size_t)(h * D + e) * D);
  const float4* Q4 = (const float4*)Q;
  float acc = 0.f;
#pragma unroll
  for (int i = 0; i < 4; ++i) {
    float4 w = Wrow[lane + i * 64];
    float4 qv = Q4[lane + i * 64];
    acc += w.x * qv.x + w.y * qv.y + w.z * qv.z + w.w * qv.w;
  }
#pragma unroll
  for (int off = 32; off; off >>= 1) acc += __shfl_xor(acc, off, 64);
  if (lane == 0) q_out[h * D + e] = acc + bQ[h * D + e];
}

// ---------------------------------------------------------------------------
// Kernel B: p[h,d] += sum_{e in chunk} q[h,e] * WK[h,e,d]
// grid (64 e-chunks of 16, 8 heads) = 512 blocks; each thread owns 4 consecutive d.
__global__ __launch_bounds__(256) void pproj_kernel(
    const float* __restrict__ q, const float* __restrict__ WK,
    float* __restrict__ p) {
  int h = blockIdx.y;
  int e0 = blockIdx.x * 16;
  __shared__ float qc[16];
  if (threadIdx.x < 16) qc[threadIdx.x] = q[h * D + e0 + threadIdx.x];
  __syncthreads();
  const float4* W4 = (const float4*)(WK + (size_t)h * D * D);
  float4 acc = {0.f, 0.f, 0.f, 0.f};
#pragma unroll 4
  for (int ee = 0; ee < 16; ++ee) {
    float4 w = W4[(size_t)(e0 + ee) * (D / 4) + threadIdx.x];
    float qe = qc[ee];
    acc.x += qe * w.x;
    acc.y += qe * w.y;
    acc.z += qe * w.z;
    acc.w += qe * w.w;
  }
  float* pd = p + h * D + threadIdx.x * 4;
  atomicAdd(pd + 0, acc.x);
  atomicAdd(pd + 1, acc.y);
  atomicAdd(pd + 2, acc.z);
  atomicAdd(pd + 3, acc.w);
}

// ---------------------------------------------------------------------------
// Kernel B2: bkdot[h] = sum_e q[h,e]*bK[h,e]. One wave per head, 1 block of 512.
__global__ __launch_bounds__(512) void bkdot_kernel(
    const float* __restrict__ q, const float* __restrict__ bK,
    float* __restrict__ bkdot) {
  int h = threadIdx.x >> 6;
  int lane = threadIdx.x & 63;
  const float4* q4 = (const float4*)(q + h * D);
  const float4* b4 = (const float4*)(bK + h * D);
  float acc = 0.f;
#pragma unroll
  for (int i = 0; i < 4; ++i) {
    float4 a = q4[lane + i * 64];
    float4 b = b4[lane + i * 64];
    acc += a.x * b.x + a.y * b.y + a.z * b.z + a.w * b.w;
  }
#pragma unroll
  for (int off = 32; off; off >>= 1) acc += __shfl_xor(acc, off, 64);
  if (lane == 0) bkdot[h] = acc;
}

// ---------------------------------------------------------------------------
// Kernel C: logits[h,m] = (K[m,:] . p[h,:] + bkdot[h]) / 1024
// One wave per m (all 8 heads together). 2048 waves -> 512 blocks of 256.
__global__ __launch_bounds__(256) void logits_kernel(
    const float* __restrict__ K, const float* __restrict__ p,
    const float* __restrict__ bkdot, float* __restrict__ logits) {
  int wave = (blockIdx.x * 256 + threadIdx.x) >> 6;
  int lane = threadIdx.x & 63;
  int m = wave;
  const float4* K4 = (const float4*)(K + (size_t)m * D);
  float acc[H];
#pragma unroll
  for (int h = 0; h < H; ++h) acc[h] = 0.f;
#pragma unroll
  for (int i = 0; i < 4; ++i) {
    float4 kv = K4[lane + i * 64];
#pragma unroll
    for (int h = 0; h < H; ++h) {
      float4 pv = ((const float4*)(p + h * D))[lane + i * 64];
      acc[h] += kv.x * pv.x + kv.y * pv.y + kv.z * pv.z + kv.w * pv.w;
    }
  }
#pragma unroll
  for (int h = 0; h < H; ++h) {
    float a = acc[h];
#pragma unroll
    for (int off = 32; off; off >>= 1) a += __shfl_xor(a, off, 64);
    if (lane == 0) logits[h * M + m] = (a + bkdot[h]) * (1.0f / (float)D);
  }
}

// ---------------------------------------------------------------------------
// Kernel D: softmax over m per head. 8 blocks of 256 (8 elements/thread).
__global__ __launch_bounds__(256) void softmax_kernel(
    const float* __restrict__ logits, float* __restrict__ w) {
  int h = blockIdx.x;
  int lane = threadIdx.x & 63;
  int wid = threadIdx.x >> 6;
  __shared__ float sred[8];
  float l[8];
  float mx = -1e30f;
#pragma unroll
  for (int i = 0; i < 8; ++i) {
    l[i] = logits[h * M + threadIdx.x + i * 256];
    mx = fmaxf(mx, l[i]);
  }
#pragma unroll
  for (int off = 32; off; off >>= 1) mx = fmaxf(mx, __shfl_xor(mx, off, 64));
  if (lane == 0) sred[wid] = mx;
  __syncthreads();
  float bmax = fmaxf(fmaxf(sred[0], sred[1]), fmaxf(sred[2], sred[3]));
  float ev[8];
  float s = 0.f;
#pragma unroll
  for (int i = 0; i < 8; ++i) {
    ev[i] = __expf(l[i] - bmax);
    s += ev[i];
  }
#pragma unroll
  for (int off = 32; off; off >>= 1) s += __shfl_xor(s, off, 64);
  if (lane == 0) sred[4 + wid] = s;
  __syncthreads();
  float tot = sred[4] + sred[5] + sred[6] + sred[7];
  float inv = 1.0f / tot;
#pragma unroll
  for (int i = 0; i < 8; ++i)
    w[h * M + threadIdx.x + i * 256] = ev[i] * inv;
}

// ---------------------------------------------------------------------------
// Kernel E: out[h, j] += sum_{m in chunk} w[h,m] * V[m, j]
// grid (48 col-blocks, 32 m-chunks of 64) = 1536 blocks (6/CU), block 256.
// Atomic finalize stays L2-resident (out region is 1.5 MB); HBM write ~1.5 MB.
__global__ __launch_bounds__(256) void out_kernel(
    const float* __restrict__ V, const float* __restrict__ w,
    float* __restrict__ out) {
  int m0 = blockIdx.y * 64;
  int c4 = blockIdx.x * 256 + threadIdx.x;  // float4 column index [0, 12288)
  __shared__ float wc[H][64];
  for (int i = threadIdx.x; i < H * 64; i += 256)
    wc[i >> 6][i & 63] = w[(i >> 6) * M + m0 + (i & 63)];
  __syncthreads();
  const nfloat4* V4 = (const nfloat4*)V;
  float4 acc[H];
#pragma unroll
  for (int h = 0; h < H; ++h) acc[h] = make_float4(0.f, 0.f, 0.f, 0.f);
  for (int mm = 0; mm < 64; mm += 4) {
    nfloat4 v0 = __builtin_nontemporal_load(&V4[(size_t)(m0 + mm + 0) * IMG4 + c4]);
    nfloat4 v1 = __builtin_nontemporal_load(&V4[(size_t)(m0 + mm + 1) * IMG4 + c4]);
    nfloat4 v2 = __builtin_nontemporal_load(&V4[(size_t)(m0 + mm + 2) * IMG4 + c4]);
    nfloat4 v3 = __builtin_nontemporal_load(&V4[(size_t)(m0 + mm + 3) * IMG4 + c4]);
#pragma unroll
    for (int h = 0; h < H; ++h) {
      float w0 = wc[h][mm + 0];
      float w1 = wc[h][mm + 1];
      float w2 = wc[h][mm + 2];
      float w3 = wc[h][mm + 3];
      acc[h].x += w0 * v0.x + w1 * v1.x + w2 * v2.x + w3 * v3.x;
      acc[h].y += w0 * v0.y + w1 * v1.y + w2 * v2.y + w3 * v3.y;
      acc[h].z += w0 * v0.z + w1 * v1.z + w2 * v2.z + w3 * v3.z;
      acc[h].w += w0 * v0.w + w1 * v1.w + w2 * v2.w + w3 * v3.w;
    }
  }
#pragma unroll
  for (int h = 0; h < H; ++h) {
    float* o = out + (size_t)h * IMG + c4 * 4;
    atomicAdd(o + 0, acc[h].x);
    atomicAdd(o + 1, acc[h].y);
    atomicAdd(o + 2, acc[h].z);
    atomicAdd(o + 3, acc[h].w);
  }
}

// ---------------------------------------------------------------------------
extern "C" void kernel_launch(void* const* d_in, const int* in_sizes, int n_in,
                              void* d_out, int out_size, void* d_ws, size_t ws_size,
                              hipStream_t stream) {
  const float* Q  = (const float*)d_in[0];
  const float* K  = (const float*)d_in[1];
  const float* V  = (const float*)d_in[2];
  const float* WQ = (const float*)d_in[3];
  const float* bQ = (const float*)d_in[4];
  const float* WK = (const float*)d_in[5];
  const float* bK = (const float*)d_in[6];
  float* out = (float*)d_out;
  float* ws = (float*)d_ws;

  float* q_ws     = ws + WS_Q;
  float* p_ws     = ws + WS_P;
  float* bk_ws    = ws + WS_BK;
  float* log_ws   = ws + WS_LOGITS;
  float* w_ws     = ws + WS_W;

  // zero the atomic targets
  (void)hipMemsetAsync(p_ws, 0, (size_t)H * D * sizeof(float), stream);
  (void)hipMemsetAsync(out, 0, (size_t)H * IMG * sizeof(float), stream);

  qproj_kernel<<<dim3(2048), dim3(256), 0, stream>>>(Q, WQ, bQ, q_ws);
  pproj_kernel<<<dim3(64, H), dim3(256), 0, stream>>>(q_ws, WK, p_ws);
  bkdot_kernel<<<dim3(1), dim3(512), 0, stream>>>(q_ws, bK, bk_ws);
  logits_kernel<<<dim3(512), dim3(256), 0, stream>>>(K, p_ws, bk_ws, log_ws);
  softmax_kernel<<<dim3(H), dim3(256), 0, stream>>>(log_ws, w_ws);
  out_kernel<<<dim3(48, 32), dim3(256), 0, stream>>>(V, w_ws, out);
}

// Round 4
// 584.486 us; speedup vs baseline: 1.2691x; 1.2691x over previous
//
#include <hip/hip_runtime.h>

// Problem constants
#define D     1024
#define H     8
#define M     2048
#define IMG   49152          // 128*128*3
#define IMG4  12288          // IMG/4
#define NC    16             // m-chunks for out partial stage (128 m each)

typedef float nfloat4 __attribute__((ext_vector_type(4)));  // native vec for nontemporal builtins

// Workspace layout (in floats)
#define WS_Q      0          // [H*D]       = 8192
#define WS_P      8192       // [H*D]       = 8192  (atomic-accumulated, must be zeroed)
#define WS_BK     16384      // [H]         (padded to 64)
#define WS_LOGITS 16448      // [H*M]       = 16384
#define WS_W      32832      // [H*M]       = 16384
#define WS_PART   65536      // [NC*H*IMG]  = 6,291,456 floats (25 MB)

// ---------------------------------------------------------------------------
// Kernel A: q[h,e] = sum_d Q[d]*WQ[h,e,d] + bQ[h,e]
// One wave per (h,e). 8192 waves -> 2048 blocks of 256.
__global__ __launch_bounds__(256) void qproj_kernel(
    const float* __restrict__ Q, const float* __restrict__ WQ,
    const float* __restrict__ bQ, float* __restrict__ q_out) {
  int wave = (blockIdx.x * 256 + threadIdx.x) >> 6;
  int lane = threadIdx.x & 63;
  int h = wave >> 10;
  int e = wave & 1023;
  const float4* Wrow = (const float4*)(WQ + (size_t)(h * D + e) * D);
  const float4* Q4 = (const float4*)Q;
  float acc = 0.f;
#pragma unroll
  for (int i = 0; i < 4; ++i) {
    float4 w = Wrow[lane + i * 64];
    float4 qv = Q4[lane + i * 64];
    acc += w.x * qv.x + w.y * qv.y + w.z * qv.z + w.w * qv.w;
  }
#pragma unroll
  for (int off = 32; off; off >>= 1) acc += __shfl_xor(acc, off, 64);
  if (lane == 0) q_out[h * D + e] = acc + bQ[h * D + e];
}

// ---------------------------------------------------------------------------
// Kernel B: p[h,d] += sum_{e in chunk} q[h,e] * WK[h,e,d]
// grid (64 e-chunks of 16, 8 heads) = 512 blocks; each thread owns 4 consecutive d.
// Atomics: only 512K small RMWs to a 32 KB region — acceptable.
__global__ __launch_bounds__(256) void pproj_kernel(
    const float* __restrict__ q, const float* __restrict__ WK,
    float* __restrict__ p) {
  int h = blockIdx.y;
  int e0 = blockIdx.x * 16;
  __shared__ float qc[16];
  if (threadIdx.x < 16) qc[threadIdx.x] = q[h * D + e0 + threadIdx.x];
  __syncthreads();
  const float4* W4 = (const float4*)(WK + (size_t)h * D * D);
  float4 acc = {0.f, 0.f, 0.f, 0.f};
#pragma unroll 4
  for (int ee = 0; ee < 16; ++ee) {
    float4 w = W4[(size_t)(e0 + ee) * (D / 4) + threadIdx.x];
    float qe = qc[ee];
    acc.x += qe * w.x;
    acc.y += qe * w.y;
    acc.z += qe * w.z;
    acc.w += qe * w.w;
  }
  float* pd = p + h * D + threadIdx.x * 4;
  atomicAdd(pd + 0, acc.x);
  atomicAdd(pd + 1, acc.y);
  atomicAdd(pd + 2, acc.z);
  atomicAdd(pd + 3, acc.w);
}

// ---------------------------------------------------------------------------
// Kernel B2: bkdot[h] = sum_e q[h,e]*bK[h,e]. One wave per head, 1 block of 512.
__global__ __launch_bounds__(512) void bkdot_kernel(
    const float* __restrict__ q, const float* __restrict__ bK,
    float* __restrict__ bkdot) {
  int h = threadIdx.x >> 6;
  int lane = threadIdx.x & 63;
  const float4* q4 = (const float4*)(q + h * D);
  const float4* b4 = (const float4*)(bK + h * D);
  float acc = 0.f;
#pragma unroll
  for (int i = 0; i < 4; ++i) {
    float4 a = q4[lane + i * 64];
    float4 b = b4[lane + i * 64];
    acc += a.x * b.x + a.y * b.y + a.z * b.z + a.w * b.w;
  }
#pragma unroll
  for (int off = 32; off; off >>= 1) acc += __shfl_xor(acc, off, 64);
  if (lane == 0) bkdot[h] = acc;
}

// ---------------------------------------------------------------------------
// Kernel C: logits[h,m] = (K[m,:] . p[h,:] + bkdot[h]) / 1024
// One wave per m (all 8 heads together). 2048 waves -> 512 blocks of 256.
__global__ __launch_bounds__(256) void logits_kernel(
    const float* __restrict__ K, const float* __restrict__ p,
    const float* __restrict__ bkdot, float* __restrict__ logits) {
  int wave = (blockIdx.x * 256 + threadIdx.x) >> 6;
  int lane = threadIdx.x & 63;
  int m = wave;
  const float4* K4 = (const float4*)(K + (size_t)m * D);
  float acc[H];
#pragma unroll
  for (int h = 0; h < H; ++h) acc[h] = 0.f;
#pragma unroll
  for (int i = 0; i < 4; ++i) {
    float4 kv = K4[lane + i * 64];
#pragma unroll
    for (int h = 0; h < H; ++h) {
      float4 pv = ((const float4*)(p + h * D))[lane + i * 64];
      acc[h] += kv.x * pv.x + kv.y * pv.y + kv.z * pv.z + kv.w * pv.w;
    }
  }
#pragma unroll
  for (int h = 0; h < H; ++h) {
    float a = acc[h];
#pragma unroll
    for (int off = 32; off; off >>= 1) a += __shfl_xor(a, off, 64);
    if (lane == 0) logits[h * M + m] = (a + bkdot[h]) * (1.0f / (float)D);
  }
}

// ---------------------------------------------------------------------------
// Kernel D: softmax over m per head. 8 blocks of 256 (8 elements/thread).
__global__ __launch_bounds__(256) void softmax_kernel(
    const float* __restrict__ logits, float* __restrict__ w) {
  int h = blockIdx.x;
  int lane = threadIdx.x & 63;
  int wid = threadIdx.x >> 6;
  __shared__ float sred[8];
  float l[8];
  float mx = -1e30f;
#pragma unroll
  for (int i = 0; i < 8; ++i) {
    l[i] = logits[h * M + threadIdx.x + i * 256];
    mx = fmaxf(mx, l[i]);
  }
#pragma unroll
  for (int off = 32; off; off >>= 1) mx = fmaxf(mx, __shfl_xor(mx, off, 64));
  if (lane == 0) sred[wid] = mx;
  __syncthreads();
  float bmax = fmaxf(fmaxf(sred[0], sred[1]), fmaxf(sred[2], sred[3]));
  float ev[8];
  float s = 0.f;
#pragma unroll
  for (int i = 0; i < 8; ++i) {
    ev[i] = __expf(l[i] - bmax);
    s += ev[i];
  }
#pragma unroll
  for (int off = 32; off; off >>= 1) s += __shfl_xor(s, off, 64);
  if (lane == 0) sred[4 + wid] = s;
  __syncthreads();
  float tot = sred[4] + sred[5] + sred[6] + sred[7];
  float inv = 1.0f / tot;
#pragma unroll
  for (int i = 0; i < 8; ++i)
    w[h * M + threadIdx.x + i * 256] = ev[i] * inv;
}

// ---------------------------------------------------------------------------
// Kernel E1: partials[mc][h][j] = sum_{m in chunk of 128} w[h,m] * V[m,j]
// grid (48 col-blocks, NC=16 m-chunks) = 768 blocks (3/CU), block 256.
// NO atomics: plain nontemporal stores. m-loop unrolled x8 for loads in flight.
__global__ __launch_bounds__(256) void out_partial_kernel(
    const float* __restrict__ V, const float* __restrict__ w,
    float* __restrict__ part) {
  int mc = blockIdx.y;
  int m0 = mc * 128;
  int c4 = blockIdx.x * 256 + threadIdx.x;  // float4 column index [0, 12288)
  __shared__ float wc[H][128];
  for (int i = threadIdx.x; i < H * 128; i += 256)
    wc[i >> 7][i & 127] = w[(i >> 7) * M + m0 + (i & 127)];
  __syncthreads();
  const nfloat4* V4 = (const nfloat4*)V;
  float4 acc[H];
#pragma unroll
  for (int h = 0; h < H; ++h) acc[h] = make_float4(0.f, 0.f, 0.f, 0.f);
  for (int mm = 0; mm < 128; mm += 8) {
    nfloat4 v[8];
#pragma unroll
    for (int j = 0; j < 8; ++j)
      v[j] = __builtin_nontemporal_load(&V4[(size_t)(m0 + mm + j) * IMG4 + c4]);
#pragma unroll
    for (int h = 0; h < H; ++h) {
#pragma unroll
      for (int j = 0; j < 8; ++j) {
        float wj = wc[h][mm + j];
        acc[h].x += wj * v[j].x;
        acc[h].y += wj * v[j].y;
        acc[h].z += wj * v[j].z;
        acc[h].w += wj * v[j].w;
      }
    }
  }
  nfloat4* P4 = (nfloat4*)part;
#pragma unroll
  for (int h = 0; h < H; ++h) {
    nfloat4 o = {acc[h].x, acc[h].y, acc[h].z, acc[h].w};
    __builtin_nontemporal_store(o, &P4[((size_t)mc * H + h) * IMG4 + c4]);
  }
}

// ---------------------------------------------------------------------------
// Kernel E2: out[h][j] = sum_mc partials[mc][h][j]. 384 blocks of 256.
__global__ __launch_bounds__(256) void out_reduce_kernel(
    const float* __restrict__ part, float* __restrict__ out) {
  int idx = blockIdx.x * 256 + threadIdx.x;  // float4 index into H*IMG4 = 98304
  const nfloat4* P4 = (const nfloat4*)part;
  float4 s = make_float4(0.f, 0.f, 0.f, 0.f);
#pragma unroll
  for (int mc = 0; mc < NC; ++mc) {
    nfloat4 v = __builtin_nontemporal_load(&P4[(size_t)mc * (H * IMG4) + idx]);
    s.x += v.x; s.y += v.y; s.z += v.z; s.w += v.w;
  }
  nfloat4 o = {s.x, s.y, s.z, s.w};
  __builtin_nontemporal_store(o, &((nfloat4*)out)[idx]);
}

// ---------------------------------------------------------------------------
extern "C" void kernel_launch(void* const* d_in, const int* in_sizes, int n_in,
                              void* d_out, int out_size, void* d_ws, size_t ws_size,
                              hipStream_t stream) {
  const float* Q  = (const float*)d_in[0];
  const float* K  = (const float*)d_in[1];
  const float* V  = (const float*)d_in[2];
  const float* WQ = (const float*)d_in[3];
  const float* bQ = (const float*)d_in[4];
  const float* WK = (const float*)d_in[5];
  const float* bK = (const float*)d_in[6];
  float* out = (float*)d_out;
  float* ws = (float*)d_ws;

  float* q_ws     = ws + WS_Q;
  float* p_ws     = ws + WS_P;
  float* bk_ws    = ws + WS_BK;
  float* log_ws   = ws + WS_LOGITS;
  float* w_ws     = ws + WS_W;
  float* part_ws  = ws + WS_PART;

  // zero the atomic target (p only; out path is atomic-free now)
  (void)hipMemsetAsync(p_ws, 0, (size_t)H * D * sizeof(float), stream);

  qproj_kernel<<<dim3(2048), dim3(256), 0, stream>>>(Q, WQ, bQ, q_ws);
  pproj_kernel<<<dim3(64, H), dim3(256), 0, stream>>>(q_ws, WK, p_ws);
  bkdot_kernel<<<dim3(1), dim3(512), 0, stream>>>(q_ws, bK, bk_ws);
  logits_kernel<<<dim3(512), dim3(256), 0, stream>>>(K, p_ws, bk_ws, log_ws);
  softmax_kernel<<<dim3(H), dim3(256), 0, stream>>>(log_ws, w_ws);
  out_partial_kernel<<<dim3(48, NC), dim3(256), 0, stream>>>(V, w_ws, part_ws);
  out_reduce_kernel<<<dim3(384), dim3(256), 0, stream>>>(part_ws, out);
}